// Round 4
// baseline (319.374 us; speedup 1.0000x reference)
//
#include <hip/hip_runtime.h>
#include <math.h>

typedef float v2 __attribute__((ext_vector_type(2)));

__device__ __forceinline__ float rcp1_(float x) { return __fdividef(1.0f, x); }
__device__ __forceinline__ v2 v2s(float s) { return (v2){s, s}; }
__device__ __forceinline__ v2 expv(v2 x) { return (v2){__expf(x.x), __expf(x.y)}; }
__device__ __forceinline__ v2 logv(v2 x) { return (v2){__logf(x.x), __logf(x.y)}; }
__device__ __forceinline__ v2 rcpv(v2 x) { return (v2){rcp1_(x.x), rcp1_(x.y)}; }
__device__ __forceinline__ v2 maxv(v2 a, v2 b) { return __builtin_elementwise_max(a, b); }
__device__ __forceinline__ v2 minv(v2 a, v2 b) { return __builtin_elementwise_min(a, b); }
__device__ __forceinline__ v2 absv(v2 a) { return (v2){__builtin_fabsf(a.x), __builtin_fabsf(a.y)}; }

// componentwise select: (x >= e) ? a : b
__device__ __forceinline__ v2 selge(v2 x, v2 e, v2 a, v2 b) {
    v2 r;
    r.x = (x.x >= e.x) ? a.x : b.x;
    r.y = (x.y >= e.y) ? a.y : b.y;
    return r;
}

__device__ __forceinline__ v2 tanhv(v2 x) {
    v2 e = expv(x + x);
    return v2s(1.0f) - v2s(2.0f) * rcpv(e + v2s(1.0f));
}

__device__ __forceinline__ v2 spv(v2 x) {   // softplus
    return maxv(x, v2s(0.0f)) + logv(v2s(1.0f) + expv(-absv(x)));
}

// w[k] = 0.001 + 0.995 * softmax(6 * softmax(o))[k]; max of inner-scaled vec is 6/s
__device__ __forceinline__ void dsm5v(v2 o0, v2 o1, v2 o2, v2 o3, v2 o4, v2* __restrict__ w) {
    v2 m = maxv(maxv(maxv(o0, o1), maxv(o2, o3)), o4);
    v2 e0 = expv(o0 - m), e1 = expv(o1 - m), e2 = expv(o2 - m),
       e3 = expv(o3 - m), e4 = expv(o4 - m);
    v2 inv = v2s(6.0f) * rcpv(((e0 + e1) + (e2 + e3)) + e4);
    v2 f0 = expv(e0 * inv - inv);
    v2 f1 = expv(e1 * inv - inv);
    v2 f2 = expv(e2 * inv - inv);
    v2 f3 = expv(e3 * inv - inv);
    v2 f4 = expv(e4 * inv - inv);
    v2 t = v2s(0.995f) * rcpv(((f0 + f1) + (f2 + f3)) + f4);
    w[0] = f0 * t + v2s(0.001f);
    w[1] = f1 * t + v2s(0.001f);
    w[2] = f2 * t + v2s(0.001f);
    w[3] = f3 * t + v2s(0.001f);
    w[4] = f4 * t + v2s(0.001f);
}

// 23 -> 8 tanh -> 8 tanh, weights wave-uniform (scalar), activations packed 2-sample
__device__ __forceinline__ void mlp2v(const float* __restrict__ W1, const float* __restrict__ b1,
                                      const float* __restrict__ W2, const float* __restrict__ b2,
                                      const v2* __restrict__ cond, v2* __restrict__ h2) {
    v2 h1[8];
#pragma unroll
    for (int i = 0; i < 8; ++i) {
        v2 a = v2s(b1[i]);
#pragma unroll
        for (int c = 0; c < 23; ++c) a = v2s(W1[i * 23 + c]) * cond[c] + a;
        h1[i] = tanhv(a);
    }
#pragma unroll
    for (int i = 0; i < 8; ++i) {
        v2 a = v2s(b2[i]);
#pragma unroll
        for (int c = 0; c < 8; ++c) a = v2s(W2[i * 8 + c]) * h1[c] + a;
        h2[i] = tanhv(a);
    }
}

__global__ __launch_bounds__(256, 4)   // 4 waves/EU min -> 128 VGPR budget; stop remat squeeze
void nsf_kernel(const float* __restrict__ x_inp, const float* __restrict__ cond_inp,
                const float* __restrict__ Wi1, const float* __restrict__ bi1,
                const float* __restrict__ Wi2, const float* __restrict__ bi2,
                const float* __restrict__ Wi3, const float* __restrict__ bi3,
                const float* __restrict__ Wf1, const float* __restrict__ bf1,
                const float* __restrict__ Wf2, const float* __restrict__ bf2,
                const float* __restrict__ Wf3, const float* __restrict__ bf3,
                float* __restrict__ out, int N)
{
    int t = blockIdx.x * blockDim.x + threadIdx.x;
    int s0 = 2 * t;
    if (s0 >= N) return;
    bool has2 = (s0 + 1 < N);
    size_t r1 = has2 ? (size_t)(s0 + 1) : (size_t)s0;

    v2 xv[8];
    {
        const float4* a = (const float4*)(x_inp + (size_t)s0 * 8);
        const float4* b = (const float4*)(x_inp + r1 * 8);
        float4 a0 = a[0], a1 = a[1], b0 = b[0], b1 = b[1];
        xv[0] = (v2){a0.x, b0.x}; xv[1] = (v2){a0.y, b0.y};
        xv[2] = (v2){a0.z, b0.z}; xv[3] = (v2){a0.w, b0.w};
        xv[4] = (v2){a1.x, b1.x}; xv[5] = (v2){a1.y, b1.y};
        xv[6] = (v2){a1.z, b1.z}; xv[7] = (v2){a1.w, b1.w};
    }
    v2 cond[23];
    {
        const float4* a = (const float4*)(cond_inp + (size_t)s0 * 16);
        const float4* b = (const float4*)(cond_inp + r1 * 16);
#pragma unroll
        for (int q = 0; q < 4; ++q) {
            float4 ca = a[q], cb = b[q];
            cond[4 * q + 0] = (v2){ca.x, cb.x};
            cond[4 * q + 1] = (v2){ca.y, cb.y};
            cond[4 * q + 2] = (v2){ca.z, cb.z};
            cond[4 * q + 3] = (v2){ca.w, cb.w};
        }
    }

    v2 total = v2s(0.0f);

#pragma unroll 1
    for (int jd = 0; jd < 8; ++jd) {
#pragma unroll
        for (int q = 0; q < 7; ++q)
            cond[16 + q] = (q < jd) ? xv[q] : v2s(0.0f);

        // ---------- gaussian-base network ----------
        v2 g0, g1;
        {
            v2 h2[8];
            mlp2v(Wi1 + jd * 184, bi1 + jd * 8, Wi2 + jd * 64, bi2 + jd * 8, cond, h2);
            const float* W3 = Wi3 + jd * 16;
            const float* b3 = bi3 + jd * 2;
            g0 = v2s(b3[0]); g1 = v2s(b3[1]);
#pragma unroll
            for (int c = 0; c < 8; ++c) {
                g0 = v2s(W3[c]) * h2[c] + g0;
                g1 = v2s(W3[8 + c]) * h2[c] + g1;
            }
        }

        // ---------- flows ----------
        v2 xcur = xv[jd];
        v2 ldsum = v2s(0.0f);
#pragma unroll 1
        for (int jf = 0; jf < 2; ++jf) {
            const int nf = jd * 2 + jf;
            v2 h2[8];
            mlp2v(Wf1 + (size_t)nf * 184, bf1 + nf * 8,
                  Wf2 + (size_t)nf * 64,  bf2 + nf * 8, cond, h2);
            v2 o[14];
            {
                const float* F3  = Wf3 + (size_t)nf * 112;
                const float* fb3 = bf3 + nf * 14;
#pragma unroll
                for (int i = 0; i < 14; ++i) {
                    v2 a = v2s(fb3[i]);
#pragma unroll
                    for (int c = 0; c < 8; ++c) a = v2s(F3[i * 8 + c]) * h2[c] + a;
                    o[i] = a;
                }
            }

            // ---------- RQS spline ----------
            v2 wv[5], hv[5];
            dsm5v(o[0], o[1], o[2], o[3], o[4], wv);
            dsm5v(o[5], o[6], o[7], o[8], o[9], hv);
            v2 di1 = spv(spv(o[10])) + v2s(0.001f);
            v2 di2 = spv(spv(o[11])) + v2s(0.001f);
            v2 di3 = spv(spv(o[12])) + v2s(0.001f);
            v2 di4 = spv(spv(o[13])) + v2s(0.001f);

            v2 xc = minv(maxv(xcur, v2s(-3.0f)), v2s(3.0f));

            v2 runw = wv[0], runh = hv[0];
            v2 cwL = v2s(-3.0f), chL = v2s(-3.0f);
            v2 cwR = v2s(6.0f) * runw + v2s(-3.0f);
            v2 chR = v2s(6.0f) * runh + v2s(-3.0f);
            v2 icw = cwL, ibw = cwR - cwL, ich = chL, ihh = chR - chL;
            v2 d0 = v2s(1.0f), d1 = di1;
#pragma unroll
            for (int k = 1; k < 5; ++k) {
                cwL = cwR; chL = chR;
                runw += wv[k]; runh += hv[k];
                cwR = (k == 4) ? v2s(3.0f) : v2s(6.0f) * runw + v2s(-3.0f);
                chR = (k == 4) ? v2s(3.0f) : v2s(6.0f) * runh + v2s(-3.0f);
                v2 dk0 = (k == 1) ? di1 : (k == 2) ? di2 : (k == 3) ? di3 : di4;
                v2 dk1 = (k == 1) ? di2 : (k == 2) ? di3 : (k == 3) ? di4 : v2s(1.0f);
                icw = selge(xc, cwL, cwL, icw);
                ibw = selge(xc, cwL, cwR - cwL, ibw);
                ich = selge(xc, cwL, chL, ich);
                ihh = selge(xc, cwL, chR - chL, ihh);
                d0  = selge(xc, cwL, dk0, d0);
                d1  = selge(xc, cwL, dk1, d1);
            }

            v2 rb     = rcpv(ibw);
            v2 idelta = ihh * rb;
            v2 th     = (xc - icw) * rb;
            v2 t2     = th * th;
            v2 omt    = v2s(1.0f) - th;
            v2 tomt   = th * omt;
            v2 den    = (d0 + d1 - v2s(2.0f) * idelta) * tomt + idelta;
            v2 rden   = rcpv(den);
            v2 xn     = ihh * (idelta * t2 + d0 * tomt) * rden + ich;
            v2 num    = (idelta * idelta) *
                        (d1 * t2 + (idelta + idelta) * tomt + d0 * (omt * omt));
            v2 ldi    = logv((num * rden) * rden);

            // inside = -3 <= xcur <= 3 (componentwise)
            v2 nxt, nld;
            nxt.x = (xcur.x >= -3.0f && xcur.x <= 3.0f) ? xn.x : xcur.x;
            nxt.y = (xcur.y >= -3.0f && xcur.y <= 3.0f) ? xn.y : xcur.y;
            nld.x = (xcur.x >= -3.0f && xcur.x <= 3.0f) ? (ldsum.x + ldi.x) : ldsum.x;
            nld.y = (xcur.y >= -3.0f && xcur.y <= 3.0f) ? (ldsum.y + ldi.y) : ldsum.y;
            xcur = nxt; ldsum = nld;
        }

        // ---------- gaussian base log-prob ----------
        v2 z  = (xcur - g0) * expv(-g1);
        v2 ez = expv(-z);
        v2 lp = -(z + ez) - g1;
        lp.x = (isnan(lp.x) || isinf(lp.x)) ? -100.0f : lp.x;
        lp.y = (isnan(lp.y) || isinf(lp.y)) ? -100.0f : lp.y;
        total += ldsum + lp;
    }

    if (has2) {
        float2 st; st.x = total.x; st.y = total.y;
        *(float2*)(out + (size_t)s0) = st;
    } else {
        out[s0] = total.x;
    }
}

extern "C" void kernel_launch(void* const* d_in, const int* in_sizes, int n_in,
                              void* d_out, int out_size, void* d_ws, size_t ws_size,
                              hipStream_t stream) {
    const float* x_inp    = (const float*)d_in[0];
    const float* cond_inp = (const float*)d_in[1];
    const float* Wi1 = (const float*)d_in[2];
    const float* bi1 = (const float*)d_in[3];
    const float* Wi2 = (const float*)d_in[4];
    const float* bi2 = (const float*)d_in[5];
    const float* Wi3 = (const float*)d_in[6];
    const float* bi3 = (const float*)d_in[7];
    const float* Wf1 = (const float*)d_in[8];
    const float* bf1 = (const float*)d_in[9];
    const float* Wf2 = (const float*)d_in[10];
    const float* bf2 = (const float*)d_in[11];
    const float* Wf3 = (const float*)d_in[12];
    const float* bf3 = (const float*)d_in[13];
    float* out = (float*)d_out;

    int N = out_size;
    int nthreads = (N + 1) / 2;
    int block = 256;
    int grid = (nthreads + block - 1) / block;
    hipLaunchKernelGGL(nsf_kernel, dim3(grid), dim3(block), 0, stream,
                       x_inp, cond_inp, Wi1, bi1, Wi2, bi2, Wi3, bi3,
                       Wf1, bf1, Wf2, bf2, Wf3, bf3, out, N);
}

// Round 5
// 309.546 us; speedup vs baseline: 1.0318x; 1.0318x over previous
//
#include <hip/hip_runtime.h>
#include <math.h>

typedef float v2 __attribute__((ext_vector_type(2)));

__device__ __forceinline__ float rcp1_(float x) { return __fdividef(1.0f, x); }
__device__ __forceinline__ v2 v2s(float s) { return (v2){s, s}; }
__device__ __forceinline__ v2 expv(v2 x) { return (v2){__expf(x.x), __expf(x.y)}; }
__device__ __forceinline__ v2 logv(v2 x) { return (v2){__logf(x.x), __logf(x.y)}; }
__device__ __forceinline__ v2 rcpv(v2 x) { return (v2){rcp1_(x.x), rcp1_(x.y)}; }
__device__ __forceinline__ v2 maxv(v2 a, v2 b) { return __builtin_elementwise_max(a, b); }
__device__ __forceinline__ v2 minv(v2 a, v2 b) { return __builtin_elementwise_min(a, b); }

// componentwise select: (x >= e) ? a : b
__device__ __forceinline__ v2 selge(v2 x, v2 e, v2 a, v2 b) {
    v2 r;
    r.x = (x.x >= e.x) ? a.x : b.x;
    r.y = (x.y >= e.y) ? a.y : b.y;
    return r;
}

// tanh via [9/8] continued-fraction Pade, t = x^2; 1 rcp, no exp.
// err <= ~2e-5 for |x|<=3, <= ~2e-4 in the clamp tail — far inside tolerance.
__device__ __forceinline__ v2 tanhv(v2 x) {
    v2 t = x * x;
    v2 p = t + v2s(378.0f);
    p = p * t + v2s(17325.0f);
    p = p * t + v2s(135135.0f);
    v2 q = v2s(28.0f) * t + v2s(3150.0f);
    q = q * t + v2s(62370.0f);
    q = q * t + v2s(135135.0f);
    v2 r = (x * p) * rcpv(q);
    return minv(maxv(r, v2s(-1.0f)), v2s(1.0f));
}

// EXACT fusion: softplus(softplus(x)) = log(2 + e^x)  (args bounded, no overflow)
__device__ __forceinline__ v2 sp2v(v2 x) {
    return logv(v2s(2.0f) + expv(x));
}

// w[k] = 0.001 + 0.995 * softmax(6 * softmax(o))[k]
// softmax is shift-invariant and outer args 6*e/s are in (0,6] -> no max needed anywhere.
__device__ __forceinline__ void dsm5v(v2 o0, v2 o1, v2 o2, v2 o3, v2 o4, v2* __restrict__ w) {
    v2 e0 = expv(o0), e1 = expv(o1), e2 = expv(o2), e3 = expv(o3), e4 = expv(o4);
    v2 inv = v2s(6.0f) * rcpv(((e0 + e1) + (e2 + e3)) + e4);
    v2 f0 = expv(e0 * inv);
    v2 f1 = expv(e1 * inv);
    v2 f2 = expv(e2 * inv);
    v2 f3 = expv(e3 * inv);
    v2 f4 = expv(e4 * inv);
    v2 t = v2s(0.995f) * rcpv(((f0 + f1) + (f2 + f3)) + f4);
    w[0] = f0 * t + v2s(0.001f);
    w[1] = f1 * t + v2s(0.001f);
    w[2] = f2 * t + v2s(0.001f);
    w[3] = f3 * t + v2s(0.001f);
    w[4] = f4 * t + v2s(0.001f);
}

// 23 -> 8 tanh -> 8 tanh, weights wave-uniform (scalar), activations packed 2-sample
__device__ __forceinline__ void mlp2v(const float* __restrict__ W1, const float* __restrict__ b1,
                                      const float* __restrict__ W2, const float* __restrict__ b2,
                                      const v2* __restrict__ cond, v2* __restrict__ h2) {
    v2 h1[8];
#pragma unroll
    for (int i = 0; i < 8; ++i) {
        v2 a = v2s(b1[i]);
#pragma unroll
        for (int c = 0; c < 23; ++c) a = v2s(W1[i * 23 + c]) * cond[c] + a;
        h1[i] = tanhv(a);
    }
#pragma unroll
    for (int i = 0; i < 8; ++i) {
        v2 a = v2s(b2[i]);
#pragma unroll
        for (int c = 0; c < 8; ++c) a = v2s(W2[i * 8 + c]) * h1[c] + a;
        h2[i] = tanhv(a);
    }
}

__global__ __launch_bounds__(256)   // bare: (256,4) caused spills (R4: 49MB scratch writes)
void nsf_kernel(const float* __restrict__ x_inp, const float* __restrict__ cond_inp,
                const float* __restrict__ Wi1, const float* __restrict__ bi1,
                const float* __restrict__ Wi2, const float* __restrict__ bi2,
                const float* __restrict__ Wi3, const float* __restrict__ bi3,
                const float* __restrict__ Wf1, const float* __restrict__ bf1,
                const float* __restrict__ Wf2, const float* __restrict__ bf2,
                const float* __restrict__ Wf3, const float* __restrict__ bf3,
                float* __restrict__ out, int N)
{
    int t = blockIdx.x * blockDim.x + threadIdx.x;
    int s0 = 2 * t;
    if (s0 >= N) return;
    bool has2 = (s0 + 1 < N);
    size_t r1 = has2 ? (size_t)(s0 + 1) : (size_t)s0;

    v2 xv[8];
    {
        const float4* a = (const float4*)(x_inp + (size_t)s0 * 8);
        const float4* b = (const float4*)(x_inp + r1 * 8);
        float4 a0 = a[0], a1 = a[1], b0 = b[0], b1 = b[1];
        xv[0] = (v2){a0.x, b0.x}; xv[1] = (v2){a0.y, b0.y};
        xv[2] = (v2){a0.z, b0.z}; xv[3] = (v2){a0.w, b0.w};
        xv[4] = (v2){a1.x, b1.x}; xv[5] = (v2){a1.y, b1.y};
        xv[6] = (v2){a1.z, b1.z}; xv[7] = (v2){a1.w, b1.w};
    }
    v2 cond[23];
    {
        const float4* a = (const float4*)(cond_inp + (size_t)s0 * 16);
        const float4* b = (const float4*)(cond_inp + r1 * 16);
#pragma unroll
        for (int q = 0; q < 4; ++q) {
            float4 ca = a[q], cb = b[q];
            cond[4 * q + 0] = (v2){ca.x, cb.x};
            cond[4 * q + 1] = (v2){ca.y, cb.y};
            cond[4 * q + 2] = (v2){ca.z, cb.z};
            cond[4 * q + 3] = (v2){ca.w, cb.w};
        }
    }

    v2 total = v2s(0.0f);

#pragma unroll 1
    for (int jd = 0; jd < 8; ++jd) {
#pragma unroll
        for (int q = 0; q < 7; ++q)
            cond[16 + q] = (q < jd) ? xv[q] : v2s(0.0f);

        // ---------- gaussian-base network ----------
        v2 g0, g1;
        {
            v2 h2[8];
            mlp2v(Wi1 + jd * 184, bi1 + jd * 8, Wi2 + jd * 64, bi2 + jd * 8, cond, h2);
            const float* W3 = Wi3 + jd * 16;
            const float* b3 = bi3 + jd * 2;
            g0 = v2s(b3[0]); g1 = v2s(b3[1]);
#pragma unroll
            for (int c = 0; c < 8; ++c) {
                g0 = v2s(W3[c]) * h2[c] + g0;
                g1 = v2s(W3[8 + c]) * h2[c] + g1;
            }
        }

        // ---------- flows ----------
        v2 xcur = xv[jd];
        v2 ldsum = v2s(0.0f);
#pragma unroll 1
        for (int jf = 0; jf < 2; ++jf) {
            const int nf = jd * 2 + jf;
            v2 h2[8];
            mlp2v(Wf1 + (size_t)nf * 184, bf1 + nf * 8,
                  Wf2 + (size_t)nf * 64,  bf2 + nf * 8, cond, h2);
            v2 o[14];
            {
                const float* F3  = Wf3 + (size_t)nf * 112;
                const float* fb3 = bf3 + nf * 14;
#pragma unroll
                for (int i = 0; i < 14; ++i) {
                    v2 a = v2s(fb3[i]);
#pragma unroll
                    for (int c = 0; c < 8; ++c) a = v2s(F3[i * 8 + c]) * h2[c] + a;
                    o[i] = a;
                }
            }

            // ---------- RQS spline ----------
            v2 wv[5], hv[5];
            dsm5v(o[0], o[1], o[2], o[3], o[4], wv);
            dsm5v(o[5], o[6], o[7], o[8], o[9], hv);
            v2 di1 = sp2v(o[10]) + v2s(0.001f);
            v2 di2 = sp2v(o[11]) + v2s(0.001f);
            v2 di3 = sp2v(o[12]) + v2s(0.001f);
            v2 di4 = sp2v(o[13]) + v2s(0.001f);

            v2 xc = minv(maxv(xcur, v2s(-3.0f)), v2s(3.0f));

            v2 runw = wv[0], runh = hv[0];
            v2 cwL = v2s(-3.0f), chL = v2s(-3.0f);
            v2 cwR = v2s(6.0f) * runw + v2s(-3.0f);
            v2 chR = v2s(6.0f) * runh + v2s(-3.0f);
            v2 icw = cwL, ibw = cwR - cwL, ich = chL, ihh = chR - chL;
            v2 d0 = v2s(1.0f), d1 = di1;
#pragma unroll
            for (int k = 1; k < 5; ++k) {
                cwL = cwR; chL = chR;
                runw += wv[k]; runh += hv[k];
                cwR = (k == 4) ? v2s(3.0f) : v2s(6.0f) * runw + v2s(-3.0f);
                chR = (k == 4) ? v2s(3.0f) : v2s(6.0f) * runh + v2s(-3.0f);
                v2 dk0 = (k == 1) ? di1 : (k == 2) ? di2 : (k == 3) ? di3 : di4;
                v2 dk1 = (k == 1) ? di2 : (k == 2) ? di3 : (k == 3) ? di4 : v2s(1.0f);
                icw = selge(xc, cwL, cwL, icw);
                ibw = selge(xc, cwL, cwR - cwL, ibw);
                ich = selge(xc, cwL, chL, ich);
                ihh = selge(xc, cwL, chR - chL, ihh);
                d0  = selge(xc, cwL, dk0, d0);
                d1  = selge(xc, cwL, dk1, d1);
            }

            v2 rb     = rcpv(ibw);
            v2 idelta = ihh * rb;
            v2 th     = (xc - icw) * rb;
            v2 t2     = th * th;
            v2 omt    = v2s(1.0f) - th;
            v2 tomt   = th * omt;
            v2 den    = (d0 + d1 - v2s(2.0f) * idelta) * tomt + idelta;
            v2 rden   = rcpv(den);
            v2 xn     = ihh * (idelta * t2 + d0 * tomt) * rden + ich;
            v2 num    = (idelta * idelta) *
                        (d1 * t2 + (idelta + idelta) * tomt + d0 * (omt * omt));
            v2 ldi    = logv((num * rden) * rden);

            // inside = -3 <= xcur <= 3 (componentwise)
            v2 nxt, nld;
            nxt.x = (xcur.x >= -3.0f && xcur.x <= 3.0f) ? xn.x : xcur.x;
            nxt.y = (xcur.y >= -3.0f && xcur.y <= 3.0f) ? xn.y : xcur.y;
            nld.x = (xcur.x >= -3.0f && xcur.x <= 3.0f) ? (ldsum.x + ldi.x) : ldsum.x;
            nld.y = (xcur.y >= -3.0f && xcur.y <= 3.0f) ? (ldsum.y + ldi.y) : ldsum.y;
            xcur = nxt; ldsum = nld;
        }

        // ---------- gaussian base log-prob ----------
        v2 z  = (xcur - g0) * expv(-g1);
        v2 ez = expv(-z);
        v2 lp = -(z + ez) - g1;
        lp.x = (isnan(lp.x) || isinf(lp.x)) ? -100.0f : lp.x;
        lp.y = (isnan(lp.y) || isinf(lp.y)) ? -100.0f : lp.y;
        total += ldsum + lp;
    }

    if (has2) {
        float2 st; st.x = total.x; st.y = total.y;
        *(float2*)(out + (size_t)s0) = st;
    } else {
        out[s0] = total.x;
    }
}

extern "C" void kernel_launch(void* const* d_in, const int* in_sizes, int n_in,
                              void* d_out, int out_size, void* d_ws, size_t ws_size,
                              hipStream_t stream) {
    const float* x_inp    = (const float*)d_in[0];
    const float* cond_inp = (const float*)d_in[1];
    const float* Wi1 = (const float*)d_in[2];
    const float* bi1 = (const float*)d_in[3];
    const float* Wi2 = (const float*)d_in[4];
    const float* bi2 = (const float*)d_in[5];
    const float* Wi3 = (const float*)d_in[6];
    const float* bi3 = (const float*)d_in[7];
    const float* Wf1 = (const float*)d_in[8];
    const float* bf1 = (const float*)d_in[9];
    const float* Wf2 = (const float*)d_in[10];
    const float* bf2 = (const float*)d_in[11];
    const float* Wf3 = (const float*)d_in[12];
    const float* bf3 = (const float*)d_in[13];
    float* out = (float*)d_out;

    int N = out_size;
    int nthreads = (N + 1) / 2;
    int block = 256;
    int grid = (nthreads + block - 1) / block;
    hipLaunchKernelGGL(nsf_kernel, dim3(grid), dim3(block), 0, stream,
                       x_inp, cond_inp, Wi1, bi1, Wi2, bi2, Wi3, bi3,
                       Wf1, bf1, Wf2, bf2, Wf3, bf3, out, N);
}